// Round 5
// baseline (151.981 us; speedup 1.0000x reference)
//
#include <hip/hip_runtime.h>
#include <math.h>

// Chamfer distance on MI355X (gfx950) via f16-split MFMA.  B=8, N=M=8192, fp32.
// out = concat(dist1[B*N], dist2[B*M]).
//
// Unified pass: each 32x32 MFMA tile of unique (n,m) pairs serves BOTH
// dist1 (min over m) and dist2 (min over n).  v_mfma_f32_32x32x16_f16 K=16
// slots carry an f16-split emulation of the fp32 expansion:
//   k0..2 : qh_d * ch_d      (qh = f16(q),   ch = f16(-2c))
//   k3..5 : qh_d * cl_d      (cl = f16(-2c - ch), coord residual)
//   k6..8 : ql_d * ch_d      (ql = f16(q - qh))
//   k9,10 : |.|^2 hi/lo split (exact via fp32 accumulate)
//   k11   : 1 * 64           (bias => U > 0, so uint atomicMin is ordered)
//   k12..15: 0
// MFMA1: U1[n,m] = sq2[m] - 2q.c + 64   (min over cols -> dist1 partial)
// MFMA2: U2[n,m] = sq1[n] - 2q.c + 64   (min over rows -> dist2 partial)
// Fix-up kernel: out[i] = max(min - 64 + sq[i], 0).
//
// Fragment layouts (32x32x16): A[m=lane&31][k=(lane>>5)*8+j], B mirrored,
// C/D col=lane&31, row=(reg&3)+8*(reg>>2)+4*(lane>>5)  [verified mapping].

typedef __attribute__((ext_vector_type(8)))  _Float16 half8;
typedef __attribute__((ext_vector_type(16))) float    floatx16;

#define NPTS 8192
#define BATCH 8

// ---------------- prep: build f16-split operand records ----------------
__global__ __launch_bounds__(256) void chamfer_prep(
    const float* __restrict__ xyz1, const float* __restrict__ xyz2,
    half8* __restrict__ Alo, half8* __restrict__ Ahi1, half8* __restrict__ Ahi2,
    half8* __restrict__ Blo, half8* __restrict__ Bhi1, half8* __restrict__ Bhi2,
    float* __restrict__ sqArr, int total)   // total = BATCH*NPTS
{
    const int p = blockIdx.x * 256 + threadIdx.x;
    if (p >= total) return;

    // ---- set1 point p: A-side (rows / queries) ----
    {
        const float x = xyz1[3*p+0], y = xyz1[3*p+1], z = xyz1[3*p+2];
        _Float16 hx = (_Float16)x, hy = (_Float16)y, hz = (_Float16)z;
        _Float16 lx = (_Float16)(x - (float)hx);
        _Float16 ly = (_Float16)(y - (float)hy);
        _Float16 lz = (_Float16)(z - (float)hz);
        const float sq = fmaf(x, x, fmaf(y, y, z*z));
        _Float16 sh = (_Float16)sq;
        _Float16 sl = (_Float16)(sq - (float)sh);
        half8 lo;  lo[0]=hx; lo[1]=hy; lo[2]=hz; lo[3]=hx; lo[4]=hy; lo[5]=hz;
                   lo[6]=lx; lo[7]=ly;
        half8 h1;  h1[0]=lz; h1[1]=(_Float16)1.0f; h1[2]=(_Float16)1.0f;
                   h1[3]=(_Float16)1.0f; h1[4]=(_Float16)0.0f; h1[5]=(_Float16)0.0f;
                   h1[6]=(_Float16)0.0f; h1[7]=(_Float16)0.0f;
        half8 h2 = h1; h2[1]=sh; h2[2]=sl;            // k9,k10 = sq1 hi/lo
        Alo[p] = lo; Ahi1[p] = h1; Ahi2[p] = h2;
        sqArr[p] = sq;
    }
    // ---- set2 point p: B-side (cols / candidates), coords scaled by -2 ----
    {
        const float x = xyz2[3*p+0], y = xyz2[3*p+1], z = xyz2[3*p+2];
        const float vx = -2.f*x, vy = -2.f*y, vz = -2.f*z;
        _Float16 hx = (_Float16)vx, hy = (_Float16)vy, hz = (_Float16)vz;
        _Float16 lx = (_Float16)(vx - (float)hx);
        _Float16 ly = (_Float16)(vy - (float)hy);
        _Float16 lz = (_Float16)(vz - (float)hz);
        const float sq = fmaf(x, x, fmaf(y, y, z*z));
        _Float16 sh = (_Float16)sq;
        _Float16 sl = (_Float16)(sq - (float)sh);
        // B k-slots: k0..2=ch, k3..5=cl, k6..8=ch (k8 in hi), k9,10=sq2 split
        half8 lo;  lo[0]=hx; lo[1]=hy; lo[2]=hz; lo[3]=lx; lo[4]=ly; lo[5]=lz;
                   lo[6]=hx; lo[7]=hy;
        half8 h1;  h1[0]=hz; h1[1]=sh; h1[2]=sl; h1[3]=(_Float16)64.0f;
                   h1[4]=(_Float16)0.0f; h1[5]=(_Float16)0.0f;
                   h1[6]=(_Float16)0.0f; h1[7]=(_Float16)0.0f;
        half8 h2 = h1; h2[1]=(_Float16)1.0f; h2[2]=(_Float16)1.0f; // k9,k10 = 1
        Blo[p] = lo; Bhi1[p] = h1; Bhi2[p] = h2;
        sqArr[total + p] = sq;
    }
}

// ---------------- main: MFMA pair scan ----------------
// block = 256 = 4 waves; wave owns 2 row-tiles (64 rows); block covers
// 256 rows x 512 cols.  grid = (32, 16, 8) = 4096 blocks.
__global__ __launch_bounds__(256, 4) void chamfer_mfma(
    const half8* __restrict__ Alo, const half8* __restrict__ Ahi1,
    const half8* __restrict__ Ahi2,
    const half8* __restrict__ Blo, const half8* __restrict__ Bhi1,
    const half8* __restrict__ Bhi2,
    float* __restrict__ out)   // dist1 at [0], dist2 at [BATCH*NPTS]
{
    const int b    = blockIdx.z;
    const int lane = threadIdx.x & 63;
    const int wave = threadIdx.x >> 6;
    const int lm   = lane & 31;
    const bool hi  = lane >= 32;

    __shared__ unsigned d2min[512];
    for (int i = threadIdx.x; i < 512; i += 256) d2min[i] = 0x7f7f7f7fu;
    __syncthreads();

    // ---- A fragments (once per block): rows t0 = base..+31, t1 = +32..+63 ----
    const int row0 = blockIdx.x * 256 + wave * 64 + lm;
    const long pA0 = (long)b * NPTS + row0;
    const long pA1 = pA0 + 32;
    const half8 a1_0 = hi ? Ahi1[pA0] : Alo[pA0];
    const half8 a2_0 = hi ? Ahi2[pA0] : Alo[pA0];
    const half8 a1_1 = hi ? Ahi1[pA1] : Alo[pA1];
    const half8 a2_1 = hi ? Ahi2[pA1] : Alo[pA1];

    const int col0 = blockIdx.y * 512;
    const half8* pB1 = (hi ? Bhi1 : Blo) + (long)b * NPTS + col0 + lm;
    const half8* pB2 = (hi ? Bhi2 : Blo) + (long)b * NPTS + col0 + lm;

    floatx16 zacc;
#pragma unroll
    for (int r = 0; r < 16; ++r) zacc[r] = 0.0f;

    float mm0[16], mm1[16];
#pragma unroll
    for (int r = 0; r < 16; ++r) { mm0[r] = 3.0e38f; mm1[r] = 3.0e38f; }

    for (int t = 0; t < 16; ++t) {               // 16 col-tiles of 32
        const half8 bf1 = pB1[t * 32];
        const half8 bf2 = pB2[t * 32];

        // U1 tiles -> dist1 running mins (per row, this lane's col residue)
        floatx16 d1 = __builtin_amdgcn_mfma_f32_32x32x16_f16(a1_0, bf1, zacc, 0, 0, 0);
#pragma unroll
        for (int r = 0; r < 16; ++r) mm0[r] = fminf(mm0[r], d1[r]);
        floatx16 e1 = __builtin_amdgcn_mfma_f32_32x32x16_f16(a1_1, bf1, zacc, 0, 0, 0);
#pragma unroll
        for (int r = 0; r < 16; ++r) mm1[r] = fminf(mm1[r], e1[r]);

        // U2 tiles -> per-lane min over its 16 rows, push to per-col LDS slot
        floatx16 d2 = __builtin_amdgcn_mfma_f32_32x32x16_f16(a2_0, bf2, zacc, 0, 0, 0);
        float m = fminf(fminf(d2[0], d2[1]), d2[2]);
#pragma unroll
        for (int r = 3; r < 15; r += 2) m = fminf(fminf(d2[r], d2[r + 1]), m);
        m = fminf(m, d2[15]);
        floatx16 e2 = __builtin_amdgcn_mfma_f32_32x32x16_f16(a2_1, bf2, zacc, 0, 0, 0);
        float m2 = fminf(fminf(e2[0], e2[1]), e2[2]);
#pragma unroll
        for (int r = 3; r < 15; r += 2) m2 = fminf(fminf(e2[r], e2[r + 1]), m2);
        m2 = fminf(m2, e2[15]);
        m = fminf(m, m2);
        atomicMin(&d2min[t * 32 + lm], __float_as_uint(m));  // both halves, same col
    }

    // ---- dist1: reduce each running min across the 32 lanes of this half ----
#pragma unroll
    for (int r = 0; r < 16; ++r) {
        float v0 = mm0[r];
        v0 = fminf(v0, __shfl_xor(v0, 1));
        v0 = fminf(v0, __shfl_xor(v0, 2));
        v0 = fminf(v0, __shfl_xor(v0, 4));
        v0 = fminf(v0, __shfl_xor(v0, 8));
        v0 = fminf(v0, __shfl_xor(v0, 16));
        float v1 = mm1[r];
        v1 = fminf(v1, __shfl_xor(v1, 1));
        v1 = fminf(v1, __shfl_xor(v1, 2));
        v1 = fminf(v1, __shfl_xor(v1, 4));
        v1 = fminf(v1, __shfl_xor(v1, 8));
        v1 = fminf(v1, __shfl_xor(v1, 16));
        if (lm == 0) {
            const int rit = (r & 3) + 8 * (r >> 2) + (hi ? 4 : 0);
            const int gr0 = blockIdx.x * 256 + wave * 64 + rit;
            atomicMin((unsigned*)(out + (long)b * NPTS + gr0),
                      __float_as_uint(v0));
            atomicMin((unsigned*)(out + (long)b * NPTS + gr0 + 32),
                      __float_as_uint(v1));
        }
    }

    // ---- dist2: push per-col block partials to global ----
    __syncthreads();
    for (int i = threadIdx.x; i < 512; i += 256) {
        atomicMin((unsigned*)(out + (long)BATCH * NPTS + (long)b * NPTS + col0 + i),
                  d2min[i]);
    }
}

// ---------------- fix-up: un-bias, add |.|^2, clamp ----------------
__global__ __launch_bounds__(256) void chamfer_fix(
    float* __restrict__ out, const float* __restrict__ sqArr, int total)
{
    const int i = blockIdx.x * 256 + threadIdx.x;
    if (i < total) out[i] = fmaxf(out[i] - 64.0f + sqArr[i], 0.0f);
}

// ---------------- fallback (R2 VALU kernel, used only if ws too small) ----
#define FB_BLOCK 256
#define FB_Q 8
#define FB_QB (FB_BLOCK * FB_Q)
#define FB_CT 256
__global__ __launch_bounds__(FB_BLOCK, 8) void chamfer_valu(
    const float* __restrict__ xyz1, const float* __restrict__ xyz2,
    float* __restrict__ out, int B, int N, int M)
{
    const int z = blockIdx.z, dir = z / B, b = z % B;
    const float* qp; const float* cp; float* o; int Nq, Nc;
    if (dir == 0) { qp = xyz1 + (size_t)b*N*3; cp = xyz2 + (size_t)b*M*3;
                    o = out + (size_t)b*N; Nq = N; Nc = M; }
    else          { qp = xyz2 + (size_t)b*M*3; cp = xyz1 + (size_t)b*N*3;
                    o = out + (size_t)B*N + (size_t)b*M; Nq = M; Nc = N; }
    __shared__ float4 sc[FB_CT];
    const int c0 = blockIdx.y * FB_CT;
    for (int i = threadIdx.x; i < FB_CT; i += FB_BLOCK) {
        const int j = c0 + i;
        float x=0,y=0,zz=0,sq=3.0e38f;
        if (j < Nc) { x=cp[3*j]; y=cp[3*j+1]; zz=cp[3*j+2];
                      sq = x*x+y*y+zz*zz; }
        sc[i] = make_float4(-2.f*x, -2.f*y, -2.f*zz, sq);
    }
    __syncthreads();
    const int n0 = blockIdx.x * FB_QB + threadIdx.x;
    float qx[FB_Q], qy[FB_Q], qz[FB_Q], mm[FB_Q];
#pragma unroll
    for (int q = 0; q < FB_Q; ++q) {
        const int n = n0 + q*FB_BLOCK; float x=0,y=0,zz=0;
        if (n < Nq) { x=qp[3*n]; y=qp[3*n+1]; zz=qp[3*n+2]; }
        qx[q]=x; qy[q]=y; qz[q]=zz; mm[q]=3.0e38f;
    }
#pragma unroll 2
    for (int j = 0; j < FB_CT; j += 2) {
        const float4 ca = sc[j], cb = sc[j+1];
#pragma unroll
        for (int q = 0; q < FB_Q; ++q) {
            float t0 = fmaf(qx[q],ca.x,ca.w); t0=fmaf(qy[q],ca.y,t0); t0=fmaf(qz[q],ca.z,t0);
            float t1 = fmaf(qx[q],cb.x,cb.w); t1=fmaf(qy[q],cb.y,t1); t1=fmaf(qz[q],cb.z,t1);
            mm[q] = fminf(fminf(t0,t1), mm[q]);
        }
    }
#pragma unroll
    for (int q = 0; q < FB_Q; ++q) {
        const int n = n0 + q*FB_BLOCK;
        if (n < Nq) {
            float s = qx[q]*qx[q]; s=fmaf(qy[q],qy[q],s); s=fmaf(qz[q],qz[q],s);
            atomicMin((unsigned*)(o+n), __float_as_uint(fmaxf(s+mm[q],0.f)));
        }
    }
}

extern "C" void kernel_launch(void* const* d_in, const int* in_sizes, int n_in,
                              void* d_out, int out_size, void* d_ws, size_t ws_size,
                              hipStream_t stream) {
    const float* xyz1 = (const float*)d_in[0];
    const float* xyz2 = (const float*)d_in[1];
    float* out = (float*)d_out;
    const int total = BATCH * NPTS;              // 65536 points per set

    // out := huge positive float so uint atomicMin always wins
    hipMemsetAsync(d_out, 0x7f, (size_t)out_size * sizeof(float), stream);

    // ws layout: 6 half8 arrays (16 B/point) + sqArr (2*total floats)
    const size_t need = (size_t)total * 16 * 6 + (size_t)2 * total * 4;
    if (ws_size >= need &&
        in_sizes[0] == total * 3 && in_sizes[1] == total * 3) {
        char* w = (char*)d_ws;
        half8* Alo  = (half8*)(w);
        half8* Ahi1 = (half8*)(w + (size_t)total * 16 * 1);
        half8* Ahi2 = (half8*)(w + (size_t)total * 16 * 2);
        half8* Blo  = (half8*)(w + (size_t)total * 16 * 3);
        half8* Bhi1 = (half8*)(w + (size_t)total * 16 * 4);
        half8* Bhi2 = (half8*)(w + (size_t)total * 16 * 5);
        float* sqA  = (float*)(w + (size_t)total * 16 * 6);

        chamfer_prep<<<total / 256, 256, 0, stream>>>(
            xyz1, xyz2, Alo, Ahi1, Ahi2, Blo, Bhi1, Bhi2, sqA, total);
        dim3 grid(NPTS / 256, NPTS / 512, BATCH);   // 32 x 16 x 8
        chamfer_mfma<<<grid, 256, 0, stream>>>(
            Alo, Ahi1, Ahi2, Blo, Bhi1, Bhi2, out);
        chamfer_fix<<<(2 * total) / 256, 256, 0, stream>>>(out, sqA, 2 * total);
    } else {
        dim3 grid(NPTS / FB_QB, NPTS / FB_CT, 2 * BATCH);
        chamfer_valu<<<grid, FB_BLOCK, 0, stream>>>(
            xyz1, xyz2, out, BATCH, NPTS, NPTS);
    }
}